// Round 1
// baseline (473.374 us; speedup 1.0000x reference)
//
#include <hip/hip_runtime.h>
#include <hip/hip_bf16.h>
#include <math.h>

#define B_ 4
#define N_ 4096
#define F_ 128
#define K_ 32
#define EPS_ 1e-8f

typedef __attribute__((ext_vector_type(8))) __bf16 bf16x8;
typedef __attribute__((ext_vector_type(4))) float f32x4;

// ws float-index layout
#define WS_SSOFT 0          // N*K = 131072
#define WS_SQ    131072     // N = 4096
#define WS_SS    135168     // 1024  (zeroed)
#define WS_NUM   136192     // 4     (zeroed)
#define WS_DEN   136196     // 4     (zeroed)
#define WS_OADJ  136200     // B*K*K = 4096 (zeroed)
#define WS_WF    140296     // bf16 W_frag: B*N*64 bf16 = 2MB (524288 float-equiv)
#define WS_H     664584     // B*N ints

// ---- K1: s_soft [N,K] fp32, sq[n]=sum_k s^2, ss[K,K] += s_soft^T s_soft ----
__global__ void k_ssoft(const float* __restrict__ logits, float* __restrict__ s_soft,
                        float* __restrict__ sq, float* __restrict__ ss, float t2) {
  __shared__ float sl[64][33];
  int t = threadIdx.x;
  int rowbase = blockIdx.x * 64;
  if (t < 64) {
    int n = rowbase + t;
    float z[32];
    float mx = -1e30f;
    for (int k = 0; k < 32; ++k) { z[k] = logits[n*32+k] / t2; mx = fmaxf(mx, z[k]); }
    float s = 0.f;
    for (int k = 0; k < 32; ++k) { z[k] = expf(z[k]-mx); s += z[k]; }
    float sqa = 0.f;
    for (int k = 0; k < 32; ++k) {
      float v = z[k] / s;
      s_soft[n*32+k] = v;
      sl[t][k] = v;
      sqa += v*v;
    }
    sq[n] = sqa;
  }
  __syncthreads();
  // ss accumulation: 4 (k,l) pairs per thread over this block's 64 rows
  for (int pp = 0; pp < 4; ++pp) {
    int p = pp*256 + t;
    int k = p >> 5, l = p & 31;
    float a = 0.f;
    for (int r = 0; r < 64; ++r) a += sl[r][k]*sl[r][l];
    atomicAdd(&ss[p], a);
  }
}

// ---- K2: gumbel-softmax hard sample. writes s_sample [B,N,K] and h[b,n] ----
__global__ void k_gumbel(const float* __restrict__ logits, const float* __restrict__ gum,
                         float* __restrict__ s_sample, int* __restrict__ h, float t1) {
  int i = blockIdx.x*256 + threadIdx.x;   // [0, B*N)
  int n = i & (N_-1);
  float z[32];
  float mx = -1e30f;
  for (int k = 0; k < 32; ++k) { z[k] = logits[n*32+k]/t1 + gum[(size_t)i*32+k]; mx = fmaxf(mx, z[k]); }
  float s = 0.f;
  for (int k = 0; k < 32; ++k) { z[k] = expf(z[k]-mx); s += z[k]; }
  int am = 0; float best = -1.f;
  for (int k = 0; k < 32; ++k) { z[k] = z[k]/s; if (z[k] > best) { best = z[k]; am = k; } }
  for (int k = 0; k < 32; ++k) {
    float yh = (k==am) ? 1.f : 0.f;
    s_sample[(size_t)i*32+k] = (yh - z[k]) + z[k] + EPS_;   // straight-through value
  }
  h[i] = am;
}

// ---- K3: build W_frag in MFMA B-fragment order: [b][t][c][lane][8] bf16 ----
// cols 0..31 = s_soft (bf16), cols 32..63 = one-hot(h[b,m])
__global__ void k_wfrag(const float* __restrict__ s_soft, const int* __restrict__ h,
                        bf16x8* __restrict__ wf) {
  int i = blockIdx.x*256 + threadIdx.x;   // [0, 4*128*4*64)
  int lane = i & 63;
  int c = (i >> 6) & 3;
  int tt = (i >> 8) & 127;
  int b = i >> 15;
  int col = c*16 + (lane & 15);
  int m0 = tt*32 + (lane >> 4)*8;
  bf16x8 v;
  if (col < 32) {
    for (int j = 0; j < 8; ++j) v[j] = (__bf16)s_soft[(m0+j)*32 + col];
  } else {
    int cc = col - 32;
    for (int j = 0; j < 8; ++j) v[j] = (__bf16)((h[b*N_ + m0 + j] == cc) ? 1.f : 0.f);
  }
  wf[i] = v;
}

// ---- K4: Y = adj @ [s_soft | H], fused reductions. grid = B*32*4 = 512 blocks ----
// block: 128 rows x 64 cols, split-m over 4 chunks of 1024. 4 waves of 32 rows.
__launch_bounds__(256, 2)
__global__ void k_gemm(const float* __restrict__ adj, const bf16x8* __restrict__ wf,
                       const float* __restrict__ s_soft, const float* __restrict__ sq,
                       const int* __restrict__ h, float* __restrict__ num,
                       float* __restrict__ den, float* __restrict__ oadj) {
  __shared__ float oal[1024];     // out_adj partial [32][32]
  __shared__ float rn[4], rd[4];
  int t = threadIdx.x;
  int w = t >> 6, l = t & 63;
  int lr = l & 15, lhi = l >> 4;
  int bid = blockIdx.x;
  int sp = bid & 3, r = (bid >> 2) & 31, b = bid >> 7;

  for (int i = t; i < 1024; i += 256) oal[i] = 0.f;
  __syncthreads();

  int row0 = r*128 + w*32;
  int m0 = sp*1024;
  const float* adjb = adj + (size_t)b*N_*N_;
  const float* arow0 = adjb + (size_t)(row0 + lr)*N_ + m0 + lhi*8;
  const float* arow1 = arow0 + (size_t)16*N_;
  const bf16x8* wfb = wf + ((size_t)b*128 + (m0 >> 5))*256 + l;

  f32x4 acc[2][4];
  for (int i = 0; i < 2; ++i)
    for (int j = 0; j < 4; ++j) acc[i][j] = (f32x4){0.f,0.f,0.f,0.f};

  for (int t32 = 0; t32 < 32; ++t32) {
    float4 a0 = *(const float4*)(arow0);
    float4 a1 = *(const float4*)(arow0 + 4);
    float4 a2 = *(const float4*)(arow1);
    float4 a3 = *(const float4*)(arow1 + 4);
    bf16x8 bf0 = wfb[0], bf1 = wfb[64], bf2 = wfb[128], bf3 = wfb[192];
    bf16x8 af0, af1;
    af0[0]=(__bf16)a0.x; af0[1]=(__bf16)a0.y; af0[2]=(__bf16)a0.z; af0[3]=(__bf16)a0.w;
    af0[4]=(__bf16)a1.x; af0[5]=(__bf16)a1.y; af0[6]=(__bf16)a1.z; af0[7]=(__bf16)a1.w;
    af1[0]=(__bf16)a2.x; af1[1]=(__bf16)a2.y; af1[2]=(__bf16)a2.z; af1[3]=(__bf16)a2.w;
    af1[4]=(__bf16)a3.x; af1[5]=(__bf16)a3.y; af1[6]=(__bf16)a3.z; af1[7]=(__bf16)a3.w;
    acc[0][0] = __builtin_amdgcn_mfma_f32_16x16x32_bf16(af0, bf0, acc[0][0], 0, 0, 0);
    acc[0][1] = __builtin_amdgcn_mfma_f32_16x16x32_bf16(af0, bf1, acc[0][1], 0, 0, 0);
    acc[0][2] = __builtin_amdgcn_mfma_f32_16x16x32_bf16(af0, bf2, acc[0][2], 0, 0, 0);
    acc[0][3] = __builtin_amdgcn_mfma_f32_16x16x32_bf16(af0, bf3, acc[0][3], 0, 0, 0);
    acc[1][0] = __builtin_amdgcn_mfma_f32_16x16x32_bf16(af1, bf0, acc[1][0], 0, 0, 0);
    acc[1][1] = __builtin_amdgcn_mfma_f32_16x16x32_bf16(af1, bf1, acc[1][1], 0, 0, 0);
    acc[1][2] = __builtin_amdgcn_mfma_f32_16x16x32_bf16(af1, bf2, acc[1][2], 0, 0, 0);
    acc[1][3] = __builtin_amdgcn_mfma_f32_16x16x32_bf16(af1, bf3, acc[1][3], 0, 0, 0);
    arow0 += 32; arow1 += 32; wfb += 256;
  }

  // epilogue: C-frag lane l holds col = c*16 + (l&15), rows (l>>4)*4 + i
  float numacc = 0.f, denacc = 0.f;
  for (int rt = 0; rt < 2; ++rt) {
    int rbase = row0 + rt*16 + lhi*4;
    for (int i = 0; i < 4; ++i) {
      int row = rbase + i;
      float sqv = sq[row];
      int hv = h[b*N_ + row];
      numacc += acc[rt][0][i] * s_soft[row*32 + lr];
      numacc += acc[rt][1][i] * s_soft[row*32 + 16 + lr];
      float v2 = acc[rt][2][i], v3 = acc[rt][3][i];
      denacc += (v2 + v3) * sqv;
      atomicAdd(&oal[hv*32 + lr], v2);
      atomicAdd(&oal[hv*32 + 16 + lr], v3);
    }
  }
  for (int off = 32; off; off >>= 1) {
    numacc += __shfl_down(numacc, off);
    denacc += __shfl_down(denacc, off);
  }
  if (l == 0) { rn[w] = numacc; rd[w] = denacc; }
  __syncthreads();
  if (t == 0) {
    atomicAdd(&num[b], rn[0]+rn[1]+rn[2]+rn[3]);
    atomicAdd(&den[b], rd[0]+rd[1]+rd[2]+rd[3]);
  }
  for (int i = t; i < 1024; i += 256) atomicAdd(&oadj[b*1024 + i], oal[i]);
}

// ---- K6: out_emb[b,k,f] = sum_{n: h=k} emb[b,n,f] (LDS accum, global atomic flush) ----
__global__ void k_outemb(const float* __restrict__ emb, const int* __restrict__ h,
                         float* __restrict__ out_emb) {
  __shared__ float accl[32*128];
  int t = threadIdx.x;
  for (int i = t; i < 4096; i += 256) accl[i] = 0.f;
  __syncthreads();
  int b = blockIdx.x >> 5;
  int n0 = (blockIdx.x & 31) * 128;
  int f = t & 127, rr = t >> 7;
  for (int it = 0; it < 64; ++it) {
    int n = n0 + it*2 + rr;
    float v = emb[((size_t)b*N_ + n)*F_ + f];
    int hv = h[b*N_ + n];
    atomicAdd(&accl[hv*128 + f], v);
  }
  __syncthreads();
  for (int i = t; i < 4096; i += 256) atomicAdd(&out_emb[b*4096 + i], accl[i]);
}

// ---- K7: finalize out_adj + scalars ----
__global__ void k_final(const float* __restrict__ num, const float* __restrict__ den,
                        const float* __restrict__ oadj, const float* __restrict__ ss,
                        float* __restrict__ dout) {
  __shared__ float dsh[128];
  __shared__ float red[256];
  int t = threadIdx.x;
  if (t < 128) {
    int b = t >> 5, k = t & 31;
    float s = 0.f;
    for (int l = 0; l < 32; ++l) if (l != k) s += oadj[b*1024 + k*32 + l];
    dsh[t] = sqrtf(s) + EPS_;
  }
  __syncthreads();
  for (int i = t; i < 4096; i += 256) {
    int b = i >> 10, k = (i >> 5) & 31, l = i & 31;
    float v = (k == l) ? 0.f : oadj[i] / (dsh[b*32+k] * dsh[b*32+l]);
    dout[16384 + i] = v;
  }
  // ortho loss
  float a = 0.f;
  for (int i = t; i < 1024; i += 256) { float v = ss[i]; a += v*v; }
  red[t] = a; __syncthreads();
  for (int s2 = 128; s2; s2 >>= 1) { if (t < s2) red[t] += red[t+s2]; __syncthreads(); }
  float fro = sqrtf(red[0]);
  __syncthreads();
  float c = 0.f;
  float inv = 1.f / fro;
  float dk = (float)(1.0 / sqrt(32.0));
  for (int i = t; i < 1024; i += 256) {
    int k = i >> 5, l = i & 31;
    float v = ss[i]*inv - ((k == l) ? dk : 0.f);
    c += v*v;
  }
  red[t] = c; __syncthreads();
  for (int s2 = 128; s2; s2 >>= 1) { if (t < s2) red[t] += red[t+s2]; __syncthreads(); }
  if (t == 0) {
    dout[544769] = sqrtf(red[0]);
    float s = 0.f;
    for (int b = 0; b < 4; ++b) s += num[b]/den[b];
    dout[544768] = -s*0.25f;
  }
}

extern "C" void kernel_launch(void* const* d_in, const int* in_sizes, int n_in,
                              void* d_out, int out_size, void* d_ws, size_t ws_size,
                              hipStream_t stream) {
  const float* emb    = (const float*)d_in[0];
  const float* adj    = (const float*)d_in[1];
  const float* logits = (const float*)d_in[2];
  const float* gum    = (const float*)d_in[3];
  float* out = (float*)d_out;
  float* ws  = (float*)d_ws;

  float t1 = 0.99995f;
  float t2 = (float)(0.99995 * 0.99995);

  float* s_soft = ws + WS_SSOFT;
  float* sq     = ws + WS_SQ;
  float* ss     = ws + WS_SS;
  float* num    = ws + WS_NUM;
  float* den    = ws + WS_DEN;
  float* oadj   = ws + WS_OADJ;
  bf16x8* wf    = (bf16x8*)(ws + WS_WF);
  int* hbuf     = (int*)(ws + WS_H);

  // zero accumulators: ss(1024)+num(4)+den(4)+oadj(4096) contiguous = 5128 floats
  hipMemsetAsync(ss, 0, 5128 * sizeof(float), stream);
  // zero out_emb region of d_out (atomically accumulated)
  hipMemsetAsync(out, 0, 16384 * sizeof(float), stream);

  k_ssoft <<<64, 256, 0, stream>>>(logits, s_soft, sq, ss, t2);
  k_gumbel<<<64, 256, 0, stream>>>(logits, gum, out + 20480, hbuf, t1);
  k_wfrag <<<512, 256, 0, stream>>>(s_soft, hbuf, wf);
  k_gemm  <<<512, 256, 0, stream>>>(adj, wf, s_soft, sq, hbuf, num, den, oadj);
  k_outemb<<<128, 256, 0, stream>>>(emb, hbuf, out);
  k_final <<<1, 256, 0, stream>>>(num, den, oadj, ss, out);
}

// Round 3
// 444.765 us; speedup vs baseline: 1.0643x; 1.0643x over previous
//
#include <hip/hip_runtime.h>
#include <hip/hip_bf16.h>
#include <math.h>

#define B_ 4
#define N_ 4096
#define F_ 128
#define K_ 32
#define EPS_ 1e-8f

typedef __attribute__((ext_vector_type(8))) __bf16 bf16x8;
typedef __attribute__((ext_vector_type(4))) float f32x4;

// ws float-index layout
#define WS_SSOFT   0          // 131072
#define WS_SQ      131072     // 4096
#define WS_SS      135168     // 1024 (memset to 0)
#define WS_WF      136192     // bf16 frags: B*N*64 bf16 = 2MB = 524288 float-equiv
#define WS_OADJP   660480     // 1024 blocks * 1024 = 1048576
#define WS_NUMDEN  1709056    // 2048
#define WS_PEMB    1711104    // 128 blocks * 4096 = 524288
#define WS_OADJ    2235392    // 4096 (reduced)
#define WS_H       2239488    // B*N ints

// ---- K1: s_soft [N,K] fp32, sq[n]=sum_k s^2, ss[K,K] += s_soft^T s_soft ----
__global__ void k_ssoft(const float* __restrict__ logits, float* __restrict__ s_soft,
                        float* __restrict__ sq, float* __restrict__ ss, float t2) {
  __shared__ float sl[64][33];
  int t = threadIdx.x;
  int rowbase = blockIdx.x * 64;
  if (t < 64) {
    int n = rowbase + t;
    float z[32];
    float mx = -1e30f;
    for (int k = 0; k < 32; ++k) { z[k] = logits[n*32+k] / t2; mx = fmaxf(mx, z[k]); }
    float s = 0.f;
    for (int k = 0; k < 32; ++k) { z[k] = expf(z[k]-mx); s += z[k]; }
    float sqa = 0.f;
    for (int k = 0; k < 32; ++k) {
      float v = z[k] / s;
      s_soft[n*32+k] = v;
      sl[t][k] = v;
      sqa += v*v;
    }
    sq[n] = sqa;
  }
  __syncthreads();
  for (int pp = 0; pp < 4; ++pp) {
    int p = pp*256 + t;
    int k = p >> 5, l = p & 31;
    float a = 0.f;
    for (int r = 0; r < 64; ++r) a += sl[r][k]*sl[r][l];
    atomicAdd(&ss[p], a);
  }
}

// ---- K2: gumbel-softmax hard sample -> s_sample (d_out) + argmax h ----
__global__ void k_gumbel(const float* __restrict__ logits, const float* __restrict__ gum,
                         float* __restrict__ s_sample, int* __restrict__ h, float t1) {
  int i = blockIdx.x*256 + threadIdx.x;   // [0, B*N)
  int n = i & (N_-1);
  float z[32];
  float mx = -1e30f;
  for (int k = 0; k < 32; ++k) { z[k] = logits[n*32+k]/t1 + gum[(size_t)i*32+k]; mx = fmaxf(mx, z[k]); }
  float s = 0.f;
  for (int k = 0; k < 32; ++k) { z[k] = expf(z[k]-mx); s += z[k]; }
  int am = 0; float best = -1.f;
  for (int k = 0; k < 32; ++k) { z[k] = z[k]/s; if (z[k] > best) { best = z[k]; am = k; } }
  for (int k = 0; k < 32; ++k) {
    float yh = (k==am) ? 1.f : 0.f;
    s_sample[(size_t)i*32+k] = (yh - z[k]) + z[k] + EPS_;
  }
  h[i] = am;
}

// ---- K3: build W in MFMA B-fragment order: [b][t32][c][lane] bf16x8 ----
__global__ void k_wfrag(const float* __restrict__ s_soft, const int* __restrict__ h,
                        bf16x8* __restrict__ wf) {
  int i = blockIdx.x*256 + threadIdx.x;   // [0, 4*128*4*64)
  int lane = i & 63;
  int c = (i >> 6) & 3;
  int tt = (i >> 8) & 127;
  int b = i >> 15;
  int col = c*16 + (lane & 15);
  int m0 = tt*32 + (lane >> 4)*8;
  bf16x8 v;
  if (col < 32) {
    for (int j = 0; j < 8; ++j) v[j] = (__bf16)s_soft[(m0+j)*32 + col];
  } else {
    int cc = col - 32;
    for (int j = 0; j < 8; ++j) v[j] = (__bf16)((h[b*N_ + m0 + j] == cc) ? 1.f : 0.f);
  }
  wf[i] = v;
}

#define CVT8(dst, va, vb) { dst[0]=(__bf16)va[0]; dst[1]=(__bf16)va[1]; dst[2]=(__bf16)va[2]; dst[3]=(__bf16)va[3]; \
                            dst[4]=(__bf16)vb[0]; dst[5]=(__bf16)vb[1]; dst[6]=(__bf16)vb[2]; dst[7]=(__bf16)vb[3]; }

#define MFMA8(A0,A1,A2,A3,W0,W1,W2,W3) { \
  bf16x8 af0, af1; CVT8(af0, A0, A1); CVT8(af1, A2, A3); \
  acc00 = __builtin_amdgcn_mfma_f32_16x16x32_bf16(af0, W0, acc00, 0, 0, 0); \
  acc01 = __builtin_amdgcn_mfma_f32_16x16x32_bf16(af0, W1, acc01, 0, 0, 0); \
  acc02 = __builtin_amdgcn_mfma_f32_16x16x32_bf16(af0, W2, acc02, 0, 0, 0); \
  acc03 = __builtin_amdgcn_mfma_f32_16x16x32_bf16(af0, W3, acc03, 0, 0, 0); \
  acc10 = __builtin_amdgcn_mfma_f32_16x16x32_bf16(af1, W0, acc10, 0, 0, 0); \
  acc11 = __builtin_amdgcn_mfma_f32_16x16x32_bf16(af1, W1, acc11, 0, 0, 0); \
  acc12 = __builtin_amdgcn_mfma_f32_16x16x32_bf16(af1, W2, acc12, 0, 0, 0); \
  acc13 = __builtin_amdgcn_mfma_f32_16x16x32_bf16(af1, W3, acc13, 0, 0, 0); }

#define NT(p) __builtin_nontemporal_load((const f32x4*)(p))

// ---- K4: Y = adj @ [s_soft | H] with fused epilogue; partial stores, no global atomics ----
// grid = B * 32 rowblocks * 8 splitm = 1024; block = 128 rows x 64 cols, m-chunk 512.
__launch_bounds__(256, 4)
__global__ void k_gemm(const float* __restrict__ adj, const bf16x8* __restrict__ wf,
                       const float* __restrict__ s_soft, const float* __restrict__ sq,
                       const int* __restrict__ h, float* __restrict__ numden_p,
                       float* __restrict__ oadjp) {
  __shared__ float oal[1024];
  __shared__ float rn[4], rd[4];
  int t = threadIdx.x;
  int w = t >> 6, l = t & 63;
  int lr = l & 15, lhi = l >> 4;
  int bid = blockIdx.x;
  int sp = bid & 7, r = (bid >> 3) & 31, b = bid >> 8;

  for (int i = t; i < 1024; i += 256) oal[i] = 0.f;
  __syncthreads();

  int row0 = r*128 + w*32;
  int m0 = sp*512;
  const float* pa0 = adj + (size_t)b*N_*N_ + (size_t)(row0 + lr)*N_ + m0 + lhi*8;
  const float* pa1 = pa0 + (size_t)16*N_;
  const bf16x8* pw = wf + ((size_t)b*128 + (m0 >> 5))*256 + l;

  f32x4 acc00 = {0,0,0,0}, acc01 = {0,0,0,0}, acc02 = {0,0,0,0}, acc03 = {0,0,0,0};
  f32x4 acc10 = {0,0,0,0}, acc11 = {0,0,0,0}, acc12 = {0,0,0,0}, acc13 = {0,0,0,0};

  f32x4 xa0 = NT(pa0), xa1 = NT(pa0+4), xa2 = NT(pa1), xa3 = NT(pa1+4);
  f32x4 ya0, ya1, ya2, ya3;
  bf16x8 w0, w1, w2, w3;

  #pragma unroll 1
  for (int it = 0; it < 16; it += 2) {
    // even iter: prefetch A(it+1), compute on x
    ya0 = NT(pa0+32); ya1 = NT(pa0+36); ya2 = NT(pa1+32); ya3 = NT(pa1+36);
    w0 = pw[0]; w1 = pw[64]; w2 = pw[128]; w3 = pw[192];
    MFMA8(xa0, xa1, xa2, xa3, w0, w1, w2, w3);
    pw += 256;
    // odd iter: prefetch A(it+2), compute on y
    if (it + 2 < 16) { xa0 = NT(pa0+64); xa1 = NT(pa0+68); xa2 = NT(pa1+64); xa3 = NT(pa1+68); }
    w0 = pw[0]; w1 = pw[64]; w2 = pw[128]; w3 = pw[192];
    MFMA8(ya0, ya1, ya2, ya3, w0, w1, w2, w3);
    pw += 256;
    pa0 += 64; pa1 += 64;
  }

  // epilogue: C-frag lane l holds col = c*16 + (l&15), rows (l>>4)*4 + i (+rt*16)
  float numacc = 0.f, denacc = 0.f;
  {
    f32x4 a0s[2] = {acc00, acc10}, a1s[2] = {acc01, acc11};
    f32x4 a2s[2] = {acc02, acc12}, a3s[2] = {acc03, acc13};
    for (int rt = 0; rt < 2; ++rt) {
      int rbase = row0 + rt*16 + lhi*4;
      for (int i = 0; i < 4; ++i) {
        int row = rbase + i;
        float sqv = sq[row];
        int hv = h[b*N_ + row];
        numacc += a0s[rt][i] * s_soft[row*32 + lr];
        numacc += a1s[rt][i] * s_soft[row*32 + 16 + lr];
        float v2 = a2s[rt][i], v3 = a3s[rt][i];
        denacc += (v2 + v3) * sqv;
        atomicAdd(&oal[hv*32 + lr], v2);
        atomicAdd(&oal[hv*32 + 16 + lr], v3);
      }
    }
  }
  for (int off = 32; off; off >>= 1) {
    numacc += __shfl_down(numacc, off);
    denacc += __shfl_down(denacc, off);
  }
  if (l == 0) { rn[w] = numacc; rd[w] = denacc; }
  __syncthreads();
  if (t == 0) {
    numden_p[bid] = rn[0]+rn[1]+rn[2]+rn[3];
    numden_p[1024 + bid] = rd[0]+rd[1]+rd[2]+rd[3];
  }
  for (int i = t; i < 1024; i += 256) oadjp[(size_t)bid*1024 + i] = oal[i];
}

// ---- K5: out_emb partials: [128 blocks][32*128] ----
__global__ void k_outemb(const float* __restrict__ emb, const int* __restrict__ h,
                         float* __restrict__ pemb) {
  __shared__ float accl[32*128];
  int t = threadIdx.x;
  for (int i = t; i < 4096; i += 256) accl[i] = 0.f;
  __syncthreads();
  int b = blockIdx.x >> 5;
  int n0 = (blockIdx.x & 31) * 128;
  int f = t & 127, rr = t >> 7;
  for (int it = 0; it < 64; ++it) {
    int n = n0 + it*2 + rr;
    float v = emb[((size_t)b*N_ + n)*F_ + f];
    int hv = h[b*N_ + n];
    atomicAdd(&accl[hv*128 + f], v);
  }
  __syncthreads();
  for (int i = t; i < 4096; i += 256) pemb[(size_t)blockIdx.x*4096 + i] = accl[i];
}

// ---- K6: reduce partials (blocks 0..15: oadj; 16..79: out_emb -> d_out) ----
__global__ void k_reduce(const float* __restrict__ oadjp, const float* __restrict__ pemb,
                         float* __restrict__ oadj, float* __restrict__ out_emb) {
  int blk = blockIdx.x;
  if (blk < 16) {
    int i = blk*256 + threadIdx.x;      // [0,4096)
    int b = i >> 10, ii = i & 1023;
    float s = 0.f;
    const float* p = oadjp + (size_t)(b*256)*1024 + ii;
    for (int j = 0; j < 256; ++j) s += p[(size_t)j*1024];
    oadj[i] = s;
  } else {
    int i = (blk-16)*256 + threadIdx.x; // [0,16384)
    int b = i >> 12, ii = i & 4095;
    float s = 0.f;
    const float* p = pemb + (size_t)(b*32)*4096 + ii;
    for (int j = 0; j < 32; ++j) s += p[(size_t)j*4096];
    out_emb[i] = s;
  }
}

// ---- K7: finalize out_adj + scalars ----
__global__ void k_final(const float* __restrict__ numden_p, const float* __restrict__ oadj,
                        const float* __restrict__ ss, float* __restrict__ dout) {
  __shared__ float dsh[128];
  __shared__ float red[256];
  __shared__ float nd[8];
  int t = threadIdx.x;
  if (t < 8) {
    int b = t & 3;
    const float* p = numden_p + (t >> 2)*1024 + b*256;
    float s = 0.f;
    for (int j = 0; j < 256; ++j) s += p[j];
    nd[t] = s;
  }
  if (t >= 64 && t < 192) {
    int i = t - 64;
    int b = i >> 5, k = i & 31;
    float s = 0.f;
    for (int l = 0; l < 32; ++l) if (l != k) s += oadj[b*1024 + k*32 + l];
    dsh[i] = sqrtf(s) + EPS_;
  }
  __syncthreads();
  for (int i = t; i < 4096; i += 256) {
    int b = i >> 10, k = (i >> 5) & 31, l = i & 31;
    float v = (k == l) ? 0.f : oadj[i] / (dsh[b*32+k] * dsh[b*32+l]);
    dout[16384 + i] = v;
  }
  float a = 0.f;
  for (int i = t; i < 1024; i += 256) { float v = ss[i]; a += v*v; }
  red[t] = a; __syncthreads();
  for (int s2 = 128; s2; s2 >>= 1) { if (t < s2) red[t] += red[t+s2]; __syncthreads(); }
  float fro = sqrtf(red[0]);
  __syncthreads();
  float c = 0.f;
  float inv = 1.f / fro;
  float dk = (float)(1.0 / sqrt(32.0));
  for (int i = t; i < 1024; i += 256) {
    int k = i >> 5, l = i & 31;
    float v = ss[i]*inv - ((k == l) ? dk : 0.f);
    c += v*v;
  }
  red[t] = c; __syncthreads();
  for (int s2 = 128; s2; s2 >>= 1) { if (t < s2) red[t] += red[t+s2]; __syncthreads(); }
  if (t == 0) {
    dout[544769] = sqrtf(red[0]);
    float s = 0.f;
    for (int b = 0; b < 4; ++b) s += nd[b] / nd[4+b];
    dout[544768] = -s*0.25f;
  }
}

extern "C" void kernel_launch(void* const* d_in, const int* in_sizes, int n_in,
                              void* d_out, int out_size, void* d_ws, size_t ws_size,
                              hipStream_t stream) {
  const float* emb    = (const float*)d_in[0];
  const float* adj    = (const float*)d_in[1];
  const float* logits = (const float*)d_in[2];
  const float* gum    = (const float*)d_in[3];
  float* out = (float*)d_out;
  float* ws  = (float*)d_ws;

  float t1 = 0.99995f;
  float t2 = (float)(0.99995 * 0.99995);

  float* s_soft = ws + WS_SSOFT;
  float* sq     = ws + WS_SQ;
  float* ss     = ws + WS_SS;
  bf16x8* wf    = (bf16x8*)(ws + WS_WF);
  float* oadjp  = ws + WS_OADJP;
  float* ndp    = ws + WS_NUMDEN;
  float* pemb   = ws + WS_PEMB;
  float* oadj   = ws + WS_OADJ;
  int* hbuf     = (int*)(ws + WS_H);

  (void)hipMemsetAsync(ss, 0, 1024 * sizeof(float), stream);

  k_ssoft <<<64, 256, 0, stream>>>(logits, s_soft, sq, ss, t2);
  k_gumbel<<<64, 256, 0, stream>>>(logits, gum, out + 20480, hbuf, t1);
  k_wfrag <<<512, 256, 0, stream>>>(s_soft, hbuf, wf);
  k_gemm  <<<1024, 256, 0, stream>>>(adj, wf, s_soft, sq, hbuf, ndp, oadjp);
  k_outemb<<<128, 256, 0, stream>>>(emb, hbuf, pemb);
  k_reduce<<<80, 256, 0, stream>>>(oadjp, pemb, oadj, out);
  k_final <<<1, 256, 0, stream>>>(ndp, oadj, ss, out);
}

// Round 4
// 441.887 us; speedup vs baseline: 1.0713x; 1.0065x over previous
//
#include <hip/hip_runtime.h>
#include <hip/hip_bf16.h>
#include <math.h>

#define B_ 4
#define N_ 4096
#define F_ 128
#define K_ 32
#define EPS_ 1e-8f

typedef __attribute__((ext_vector_type(8))) __bf16 bf16x8;
typedef __attribute__((ext_vector_type(4))) float f32x4;

// ws float-index layout
#define WS_SSOFT   0          // 131072
#define WS_SQ      131072     // 4096
#define WS_SS      135168     // 1024 (memset to 0)
#define WS_WF      136192     // bf16 frags: B*N*64 bf16 = 2MB = 524288 float-equiv
#define WS_OADJP   660480     // 1024 blocks * 1024 = 1048576
#define WS_NUMDEN  1709056    // 2048
#define WS_PEMB    1711104    // 128 blocks * 4096 = 524288
#define WS_OADJ    2235392    // 4096 (reduced)
#define WS_H       2239488    // B*N ints

// ---- K1: s_soft [N,K] fp32, sq[n]=sum_k s^2, ss[K,K] += s_soft^T s_soft ----
__global__ void k_ssoft(const float* __restrict__ logits, float* __restrict__ s_soft,
                        float* __restrict__ sq, float* __restrict__ ss, float t2) {
  __shared__ float sl[64][33];
  int t = threadIdx.x;
  int rowbase = blockIdx.x * 64;
  if (t < 64) {
    int n = rowbase + t;
    float z[32];
    float mx = -1e30f;
    for (int k = 0; k < 32; ++k) { z[k] = logits[n*32+k] / t2; mx = fmaxf(mx, z[k]); }
    float s = 0.f;
    for (int k = 0; k < 32; ++k) { z[k] = expf(z[k]-mx); s += z[k]; }
    float sqa = 0.f;
    for (int k = 0; k < 32; ++k) {
      float v = z[k] / s;
      s_soft[n*32+k] = v;
      sl[t][k] = v;
      sqa += v*v;
    }
    sq[n] = sqa;
  }
  __syncthreads();
  for (int pp = 0; pp < 4; ++pp) {
    int p = pp*256 + t;
    int k = p >> 5, l = p & 31;
    float a = 0.f;
    for (int r = 0; r < 64; ++r) a += sl[r][k]*sl[r][l];
    atomicAdd(&ss[p], a);
  }
}

// ---- K2: gumbel-softmax hard sample -> s_sample (d_out) + argmax h ----
__global__ void k_gumbel(const float* __restrict__ logits, const float* __restrict__ gum,
                         float* __restrict__ s_sample, int* __restrict__ h, float t1) {
  int i = blockIdx.x*256 + threadIdx.x;   // [0, B*N)
  int n = i & (N_-1);
  float z[32];
  float mx = -1e30f;
  for (int k = 0; k < 32; ++k) { z[k] = logits[n*32+k]/t1 + gum[(size_t)i*32+k]; mx = fmaxf(mx, z[k]); }
  float s = 0.f;
  for (int k = 0; k < 32; ++k) { z[k] = expf(z[k]-mx); s += z[k]; }
  int am = 0; float best = -1.f;
  for (int k = 0; k < 32; ++k) { z[k] = z[k]/s; if (z[k] > best) { best = z[k]; am = k; } }
  for (int k = 0; k < 32; ++k) {
    float yh = (k==am) ? 1.f : 0.f;
    s_sample[(size_t)i*32+k] = (yh - z[k]) + z[k] + EPS_;
  }
  h[i] = am;
}

// ---- K3: build W in MFMA B-fragment order: [b][t32][c][lane] bf16x8 ----
__global__ void k_wfrag(const float* __restrict__ s_soft, const int* __restrict__ h,
                        bf16x8* __restrict__ wf) {
  int i = blockIdx.x*256 + threadIdx.x;   // [0, 4*128*4*64)
  int lane = i & 63;
  int c = (i >> 6) & 3;
  int tt = (i >> 8) & 127;
  int b = i >> 15;
  int col = c*16 + (lane & 15);
  int m0 = tt*32 + (lane >> 4)*8;
  bf16x8 v;
  if (col < 32) {
    for (int j = 0; j < 8; ++j) v[j] = (__bf16)s_soft[(m0+j)*32 + col];
  } else {
    int cc = col - 32;
    for (int j = 0; j < 8; ++j) v[j] = (__bf16)((h[b*N_ + m0 + j] == cc) ? 1.f : 0.f);
  }
  wf[i] = v;
}

#define CVT8(dst, va, vb) { dst[0]=(__bf16)va[0]; dst[1]=(__bf16)va[1]; dst[2]=(__bf16)va[2]; dst[3]=(__bf16)va[3]; \
                            dst[4]=(__bf16)vb[0]; dst[5]=(__bf16)vb[1]; dst[6]=(__bf16)vb[2]; dst[7]=(__bf16)vb[3]; }

#define MFMA8(A0,A1,A2,A3,W0,W1,W2,W3) { \
  bf16x8 af0, af1; CVT8(af0, A0, A1); CVT8(af1, A2, A3); \
  acc00 = __builtin_amdgcn_mfma_f32_16x16x32_bf16(af0, W0, acc00, 0, 0, 0); \
  acc01 = __builtin_amdgcn_mfma_f32_16x16x32_bf16(af0, W1, acc01, 0, 0, 0); \
  acc02 = __builtin_amdgcn_mfma_f32_16x16x32_bf16(af0, W2, acc02, 0, 0, 0); \
  acc03 = __builtin_amdgcn_mfma_f32_16x16x32_bf16(af0, W3, acc03, 0, 0, 0); \
  acc10 = __builtin_amdgcn_mfma_f32_16x16x32_bf16(af1, W0, acc10, 0, 0, 0); \
  acc11 = __builtin_amdgcn_mfma_f32_16x16x32_bf16(af1, W1, acc11, 0, 0, 0); \
  acc12 = __builtin_amdgcn_mfma_f32_16x16x32_bf16(af1, W2, acc12, 0, 0, 0); \
  acc13 = __builtin_amdgcn_mfma_f32_16x16x32_bf16(af1, W3, acc13, 0, 0, 0); }

#define NT(p) __builtin_nontemporal_load((const f32x4*)(p))

// ---- K4: Y = adj @ [s_soft | H]; both A and W register-double-buffered ----
// grid = B * 32 rowblocks * 8 splitm = 1024; block = 128 rows x 64 cols, m-chunk 512.
__launch_bounds__(256, 4)
__global__ void k_gemm(const float* __restrict__ adj, const bf16x8* __restrict__ wf,
                       const float* __restrict__ s_soft, const float* __restrict__ sq,
                       const int* __restrict__ h, float* __restrict__ numden_p,
                       float* __restrict__ oadjp) {
  __shared__ float oal[1024];
  __shared__ float rn[4], rd[4];
  int t = threadIdx.x;
  int w = t >> 6, l = t & 63;
  int lr = l & 15, lhi = l >> 4;
  int bid = blockIdx.x;
  int sp = bid & 7, r = (bid >> 3) & 31, b = bid >> 8;

  for (int i = t; i < 1024; i += 256) oal[i] = 0.f;
  __syncthreads();

  int row0 = r*128 + w*32;
  int m0 = sp*512;
  const float* pa0 = adj + (size_t)b*N_*N_ + (size_t)(row0 + lr)*N_ + m0 + lhi*8;
  const float* pa1 = pa0 + (size_t)16*N_;
  const bf16x8* pw = wf + ((size_t)b*128 + (m0 >> 5))*256 + l;

  f32x4 acc00 = {0,0,0,0}, acc01 = {0,0,0,0}, acc02 = {0,0,0,0}, acc03 = {0,0,0,0};
  f32x4 acc10 = {0,0,0,0}, acc11 = {0,0,0,0}, acc12 = {0,0,0,0}, acc13 = {0,0,0,0};

  // prime both A and W pipelines (iteration 0)
  f32x4 xa0 = NT(pa0), xa1 = NT(pa0+4), xa2 = NT(pa1), xa3 = NT(pa1+4);
  bf16x8 xw0 = pw[0], xw1 = pw[64], xw2 = pw[128], xw3 = pw[192];
  f32x4 ya0, ya1, ya2, ya3;
  bf16x8 yw0, yw1, yw2, yw3;

  #pragma unroll 1
  for (int it = 0; it < 16; it += 2) {
    // prefetch iteration it+1 (A and W) before computing on it
    ya0 = NT(pa0+32); ya1 = NT(pa0+36); ya2 = NT(pa1+32); ya3 = NT(pa1+36);
    yw0 = pw[256]; yw1 = pw[320]; yw2 = pw[384]; yw3 = pw[448];
    MFMA8(xa0, xa1, xa2, xa3, xw0, xw1, xw2, xw3);
    // prefetch iteration it+2 before computing on it+1
    if (it + 2 < 16) {
      xa0 = NT(pa0+64); xa1 = NT(pa0+68); xa2 = NT(pa1+64); xa3 = NT(pa1+68);
      xw0 = pw[512]; xw1 = pw[576]; xw2 = pw[640]; xw3 = pw[704];
    }
    MFMA8(ya0, ya1, ya2, ya3, yw0, yw1, yw2, yw3);
    pa0 += 64; pa1 += 64; pw += 512;
  }

  // epilogue: C-frag lane l holds col = c*16 + (l&15), rows (l>>4)*4 + i (+rt*16)
  float numacc = 0.f, denacc = 0.f;
  {
    f32x4 a0s[2] = {acc00, acc10}, a1s[2] = {acc01, acc11};
    f32x4 a2s[2] = {acc02, acc12}, a3s[2] = {acc03, acc13};
    for (int rt = 0; rt < 2; ++rt) {
      int rbase = row0 + rt*16 + lhi*4;
      for (int i = 0; i < 4; ++i) {
        int row = rbase + i;
        float sqv = sq[row];
        int hv = h[b*N_ + row];
        numacc += a0s[rt][i] * s_soft[row*32 + lr];
        numacc += a1s[rt][i] * s_soft[row*32 + 16 + lr];
        float v2 = a2s[rt][i], v3 = a3s[rt][i];
        denacc += (v2 + v3) * sqv;
        atomicAdd(&oal[hv*32 + lr], v2);
        atomicAdd(&oal[hv*32 + 16 + lr], v3);
      }
    }
  }
  for (int off = 32; off; off >>= 1) {
    numacc += __shfl_down(numacc, off);
    denacc += __shfl_down(denacc, off);
  }
  if (l == 0) { rn[w] = numacc; rd[w] = denacc; }
  __syncthreads();
  if (t == 0) {
    numden_p[bid] = rn[0]+rn[1]+rn[2]+rn[3];
    numden_p[1024 + bid] = rd[0]+rd[1]+rd[2]+rd[3];
  }
  for (int i = t; i < 1024; i += 256) oadjp[(size_t)bid*1024 + i] = oal[i];
}

// ---- K5: out_emb partials: [128 blocks][32*128] ----
__global__ void k_outemb(const float* __restrict__ emb, const int* __restrict__ h,
                         float* __restrict__ pemb) {
  __shared__ float accl[32*128];
  int t = threadIdx.x;
  for (int i = t; i < 4096; i += 256) accl[i] = 0.f;
  __syncthreads();
  int b = blockIdx.x >> 5;
  int n0 = (blockIdx.x & 31) * 128;
  int f = t & 127, rr = t >> 7;
  for (int it = 0; it < 64; ++it) {
    int n = n0 + it*2 + rr;
    float v = emb[((size_t)b*N_ + n)*F_ + f];
    int hv = h[b*N_ + n];
    atomicAdd(&accl[hv*128 + f], v);
  }
  __syncthreads();
  for (int i = t; i < 4096; i += 256) pemb[(size_t)blockIdx.x*4096 + i] = accl[i];
}

// ---- K6: reduce partials (blocks 0..15: oadj; 16..79: out_emb -> d_out) ----
__global__ void k_reduce(const float* __restrict__ oadjp, const float* __restrict__ pemb,
                         float* __restrict__ oadj, float* __restrict__ out_emb) {
  int blk = blockIdx.x;
  if (blk < 16) {
    int i = blk*256 + threadIdx.x;      // [0,4096)
    int b = i >> 10, ii = i & 1023;
    float s = 0.f;
    const float* p = oadjp + (size_t)(b*256)*1024 + ii;
    for (int j = 0; j < 256; ++j) s += p[(size_t)j*1024];
    oadj[i] = s;
  } else {
    int i = (blk-16)*256 + threadIdx.x; // [0,16384)
    int b = i >> 12, ii = i & 4095;
    float s = 0.f;
    const float* p = pemb + (size_t)(b*32)*4096 + ii;
    for (int j = 0; j < 32; ++j) s += p[(size_t)j*4096];
    out_emb[i] = s;
  }
}

// ---- K7: finalize out_adj + scalars ----
__global__ void k_final(const float* __restrict__ numden_p, const float* __restrict__ oadj,
                        const float* __restrict__ ss, float* __restrict__ dout) {
  __shared__ float dsh[128];
  __shared__ float red[256];
  __shared__ float nd[8];
  int t = threadIdx.x;
  if (t < 8) {
    int b = t & 3;
    const float* p = numden_p + (t >> 2)*1024 + b*256;
    float s = 0.f;
    for (int j = 0; j < 256; ++j) s += p[j];
    nd[t] = s;
  }
  if (t >= 64 && t < 192) {
    int i = t - 64;
    int b = i >> 5, k = i & 31;
    float s = 0.f;
    for (int l = 0; l < 32; ++l) if (l != k) s += oadj[b*1024 + k*32 + l];
    dsh[i] = sqrtf(s) + EPS_;
  }
  __syncthreads();
  for (int i = t; i < 4096; i += 256) {
    int b = i >> 10, k = (i >> 5) & 31, l = i & 31;
    float v = (k == l) ? 0.f : oadj[i] / (dsh[b*32+k] * dsh[b*32+l]);
    dout[16384 + i] = v;
  }
  float a = 0.f;
  for (int i = t; i < 1024; i += 256) { float v = ss[i]; a += v*v; }
  red[t] = a; __syncthreads();
  for (int s2 = 128; s2; s2 >>= 1) { if (t < s2) red[t] += red[t+s2]; __syncthreads(); }
  float fro = sqrtf(red[0]);
  __syncthreads();
  float c = 0.f;
  float inv = 1.f / fro;
  float dk = (float)(1.0 / sqrt(32.0));
  for (int i = t; i < 1024; i += 256) {
    int k = i >> 5, l = i & 31;
    float v = ss[i]*inv - ((k == l) ? dk : 0.f);
    c += v*v;
  }
  red[t] = c; __syncthreads();
  for (int s2 = 128; s2; s2 >>= 1) { if (t < s2) red[t] += red[t+s2]; __syncthreads(); }
  if (t == 0) {
    dout[544769] = sqrtf(red[0]);
    float s = 0.f;
    for (int b = 0; b < 4; ++b) s += nd[b] / nd[4+b];
    dout[544768] = -s*0.25f;
  }
}

extern "C" void kernel_launch(void* const* d_in, const int* in_sizes, int n_in,
                              void* d_out, int out_size, void* d_ws, size_t ws_size,
                              hipStream_t stream) {
  const float* emb    = (const float*)d_in[0];
  const float* adj    = (const float*)d_in[1];
  const float* logits = (const float*)d_in[2];
  const float* gum    = (const float*)d_in[3];
  float* out = (float*)d_out;
  float* ws  = (float*)d_ws;

  float t1 = 0.99995f;
  float t2 = (float)(0.99995 * 0.99995);

  float* s_soft = ws + WS_SSOFT;
  float* sq     = ws + WS_SQ;
  float* ss     = ws + WS_SS;
  bf16x8* wf    = (bf16x8*)(ws + WS_WF);
  float* oadjp  = ws + WS_OADJP;
  float* ndp    = ws + WS_NUMDEN;
  float* pemb   = ws + WS_PEMB;
  float* oadj   = ws + WS_OADJ;
  int* hbuf     = (int*)(ws + WS_H);

  (void)hipMemsetAsync(ss, 0, 1024 * sizeof(float), stream);

  k_ssoft <<<64, 256, 0, stream>>>(logits, s_soft, sq, ss, t2);
  k_gumbel<<<64, 256, 0, stream>>>(logits, gum, out + 20480, hbuf, t1);
  k_wfrag <<<512, 256, 0, stream>>>(s_soft, hbuf, wf);
  k_gemm  <<<1024, 256, 0, stream>>>(adj, wf, s_soft, sq, hbuf, ndp, oadjp);
  k_outemb<<<128, 256, 0, stream>>>(emb, hbuf, pemb);
  k_reduce<<<80, 256, 0, stream>>>(oadjp, pemb, oadj, out);
  k_final <<<1, 256, 0, stream>>>(ndp, oadj, ss, out);
}

// Round 5
// 441.406 us; speedup vs baseline: 1.0724x; 1.0011x over previous
//
#include <hip/hip_runtime.h>
#include <hip/hip_bf16.h>
#include <math.h>

#define B_ 4
#define N_ 4096
#define F_ 128
#define K_ 32
#define EPS_ 1e-8f

typedef __attribute__((ext_vector_type(8))) __bf16 bf16x8;
typedef __attribute__((ext_vector_type(4))) float f32x4;

// ws float-index layout
#define WS_SSOFT   0          // 131072
#define WS_SQ      131072     // 4096
#define WS_SS      135168     // 1024 (memset to 0)
#define WS_WF      136192     // bf16 frags: B*N*64 bf16 = 2MB = 524288 float-equiv
#define WS_OADJP   660480     // 1024 blocks * 1024 = 1048576
#define WS_NUMDEN  1709056    // 2048
#define WS_PEMB    1711104    // 128 blocks * 4096 = 524288
#define WS_OADJ    2235392    // 4096 (reduced)
#define WS_H       2239488    // B*N ints

// ---- K1: s_soft [N,K] fp32, sq[n]=sum_k s^2, ss[K,K] += s_soft^T s_soft ----
__global__ void k_ssoft(const float* __restrict__ logits, float* __restrict__ s_soft,
                        float* __restrict__ sq, float* __restrict__ ss, float t2) {
  __shared__ float sl[64][33];
  int t = threadIdx.x;
  int rowbase = blockIdx.x * 64;
  if (t < 64) {
    int n = rowbase + t;
    float z[32];
    float mx = -1e30f;
    for (int k = 0; k < 32; ++k) { z[k] = logits[n*32+k] / t2; mx = fmaxf(mx, z[k]); }
    float s = 0.f;
    for (int k = 0; k < 32; ++k) { z[k] = expf(z[k]-mx); s += z[k]; }
    float sqa = 0.f;
    for (int k = 0; k < 32; ++k) {
      float v = z[k] / s;
      s_soft[n*32+k] = v;
      sl[t][k] = v;
      sqa += v*v;
    }
    sq[n] = sqa;
  }
  __syncthreads();
  for (int pp = 0; pp < 4; ++pp) {
    int p = pp*256 + t;
    int k = p >> 5, l = p & 31;
    float a = 0.f;
    for (int r = 0; r < 64; ++r) a += sl[r][k]*sl[r][l];
    atomicAdd(&ss[p], a);
  }
}

// ---- K2: gumbel-softmax hard sample -> s_sample (d_out) + argmax h ----
__global__ void k_gumbel(const float* __restrict__ logits, const float* __restrict__ gum,
                         float* __restrict__ s_sample, int* __restrict__ h, float t1) {
  int i = blockIdx.x*256 + threadIdx.x;   // [0, B*N)
  int n = i & (N_-1);
  float z[32];
  float mx = -1e30f;
  for (int k = 0; k < 32; ++k) { z[k] = logits[n*32+k]/t1 + gum[(size_t)i*32+k]; mx = fmaxf(mx, z[k]); }
  float s = 0.f;
  for (int k = 0; k < 32; ++k) { z[k] = expf(z[k]-mx); s += z[k]; }
  int am = 0; float best = -1.f;
  for (int k = 0; k < 32; ++k) { z[k] = z[k]/s; if (z[k] > best) { best = z[k]; am = k; } }
  for (int k = 0; k < 32; ++k) {
    float yh = (k==am) ? 1.f : 0.f;
    s_sample[(size_t)i*32+k] = (yh - z[k]) + z[k] + EPS_;
  }
  h[i] = am;
}

// ---- K3: build W in MFMA B-fragment order: [b][t32][c][lane] bf16x8 ----
__global__ void k_wfrag(const float* __restrict__ s_soft, const int* __restrict__ h,
                        bf16x8* __restrict__ wf) {
  int i = blockIdx.x*256 + threadIdx.x;   // [0, 4*128*4*64)
  int lane = i & 63;
  int c = (i >> 6) & 3;
  int tt = (i >> 8) & 127;
  int b = i >> 15;
  int col = c*16 + (lane & 15);
  int m0 = tt*32 + (lane >> 4)*8;
  bf16x8 v;
  if (col < 32) {
    for (int j = 0; j < 8; ++j) v[j] = (__bf16)s_soft[(m0+j)*32 + col];
  } else {
    int cc = col - 32;
    for (int j = 0; j < 8; ++j) v[j] = (__bf16)((h[b*N_ + m0 + j] == cc) ? 1.f : 0.f);
  }
  wf[i] = v;
}

#define NT(p) __builtin_nontemporal_load((const f32x4*)(p))

union PK2 { __bf16 h[2]; unsigned int u; };
union FR8 { unsigned int u[4]; bf16x8 v; };

static __device__ __forceinline__ unsigned int pk2(float a, float b) {
  PK2 x; x.h[0] = (__bf16)a; x.h[1] = (__bf16)b; return x.u;
}

// LDS tile row stride in uints (32 bf16 data + 2 pad = 34 bf16 = 17 uints)
#define LSTRIDE 17

// ---- K4: Y = adj @ [s_soft | H]; coalesced global->reg->bf16->LDS staging ----
// grid = B * 32 rowblocks * 8 splitm = 1024; block = 128 rows x 64 cols, m-chunk 512.
// 16 K-chunks of 32, double-buffered LDS.
__launch_bounds__(256, 4)
__global__ void k_gemm(const float* __restrict__ adj, const bf16x8* __restrict__ wf,
                       const float* __restrict__ s_soft, const float* __restrict__ sq,
                       const int* __restrict__ h, float* __restrict__ numden_p,
                       float* __restrict__ oadjp) {
  __shared__ unsigned int lds[2][128*LSTRIDE];
  __shared__ float oal[1024];
  __shared__ float rn[4], rd[4];
  int t = threadIdx.x;
  int w = t >> 6, l = t & 63;
  int lr = l & 15, lhi = l >> 4;
  int bid = blockIdx.x;
  int sp = bid & 7, r = (bid >> 3) & 31, b = bid >> 8;

  for (int i = t; i < 1024; i += 256) oal[i] = 0.f;

  int row0 = r*128;
  int m0 = sp*512;

  // staging assignment: thread t covers rows rowL+32s (s=0..3), floats [colf, colf+4)
  int rowL = t >> 3;            // 0..31
  int colf = (t & 7) * 4;       // 0..28
  const float* pA = adj + (size_t)b*N_*N_ + (size_t)(row0 + rowL)*N_ + m0 + colf;
  const bf16x8* pw = wf + ((size_t)b*128 + (m0 >> 5))*256 + l;

  f32x4 acc00 = {0,0,0,0}, acc01 = {0,0,0,0}, acc02 = {0,0,0,0}, acc03 = {0,0,0,0};
  f32x4 acc10 = {0,0,0,0}, acc11 = {0,0,0,0}, acc12 = {0,0,0,0}, acc13 = {0,0,0,0};

  // prime chunk 0
  f32x4 ar0 = NT(pA);
  f32x4 ar1 = NT(pA + (size_t)32*N_);
  f32x4 ar2 = NT(pA + (size_t)64*N_);
  f32x4 ar3 = NT(pA + (size_t)96*N_);
  bf16x8 wc0 = pw[0], wc1 = pw[64], wc2 = pw[128], wc3 = pw[192];

  {
    int base = rowL*LSTRIDE + (t & 7)*2;
    lds[0][base]                 = pk2(ar0[0], ar0[1]);
    lds[0][base+1]               = pk2(ar0[2], ar0[3]);
    lds[0][base+32*LSTRIDE]      = pk2(ar1[0], ar1[1]);
    lds[0][base+32*LSTRIDE+1]    = pk2(ar1[2], ar1[3]);
    lds[0][base+64*LSTRIDE]      = pk2(ar2[0], ar2[1]);
    lds[0][base+64*LSTRIDE+1]    = pk2(ar2[2], ar2[3]);
    lds[0][base+96*LSTRIDE]      = pk2(ar3[0], ar3[1]);
    lds[0][base+96*LSTRIDE+1]    = pk2(ar3[2], ar3[3]);
  }
  __syncthreads();

  bf16x8 wn0, wn1, wn2, wn3;
  int af0base = (w*32 + lr)*LSTRIDE + lhi*4;        // rt=0 frag uint base
  int af1base = (w*32 + 16 + lr)*LSTRIDE + lhi*4;   // rt=1

  #pragma unroll 1
  for (int c = 0; c < 16; ++c) {
    int cur = c & 1;
    if (c < 15) {
      pA += 32;
      ar0 = NT(pA);
      ar1 = NT(pA + (size_t)32*N_);
      ar2 = NT(pA + (size_t)64*N_);
      ar3 = NT(pA + (size_t)96*N_);
      pw += 256;
      wn0 = pw[0]; wn1 = pw[64]; wn2 = pw[128]; wn3 = pw[192];
    }
    // A fragments from LDS
    FR8 fa0, fa1;
    fa0.u[0] = lds[cur][af0base];   fa0.u[1] = lds[cur][af0base+1];
    fa0.u[2] = lds[cur][af0base+2]; fa0.u[3] = lds[cur][af0base+3];
    fa1.u[0] = lds[cur][af1base];   fa1.u[1] = lds[cur][af1base+1];
    fa1.u[2] = lds[cur][af1base+2]; fa1.u[3] = lds[cur][af1base+3];
    acc00 = __builtin_amdgcn_mfma_f32_16x16x32_bf16(fa0.v, wc0, acc00, 0, 0, 0);
    acc01 = __builtin_amdgcn_mfma_f32_16x16x32_bf16(fa0.v, wc1, acc01, 0, 0, 0);
    acc02 = __builtin_amdgcn_mfma_f32_16x16x32_bf16(fa0.v, wc2, acc02, 0, 0, 0);
    acc03 = __builtin_amdgcn_mfma_f32_16x16x32_bf16(fa0.v, wc3, acc03, 0, 0, 0);
    acc10 = __builtin_amdgcn_mfma_f32_16x16x32_bf16(fa1.v, wc0, acc10, 0, 0, 0);
    acc11 = __builtin_amdgcn_mfma_f32_16x16x32_bf16(fa1.v, wc1, acc11, 0, 0, 0);
    acc12 = __builtin_amdgcn_mfma_f32_16x16x32_bf16(fa1.v, wc2, acc12, 0, 0, 0);
    acc13 = __builtin_amdgcn_mfma_f32_16x16x32_bf16(fa1.v, wc3, acc13, 0, 0, 0);
    if (c < 15) {
      int nxt = cur ^ 1;
      int base = rowL*LSTRIDE + (t & 7)*2;
      lds[nxt][base]                 = pk2(ar0[0], ar0[1]);
      lds[nxt][base+1]               = pk2(ar0[2], ar0[3]);
      lds[nxt][base+32*LSTRIDE]      = pk2(ar1[0], ar1[1]);
      lds[nxt][base+32*LSTRIDE+1]    = pk2(ar1[2], ar1[3]);
      lds[nxt][base+64*LSTRIDE]      = pk2(ar2[0], ar2[1]);
      lds[nxt][base+64*LSTRIDE+1]    = pk2(ar2[2], ar2[3]);
      lds[nxt][base+96*LSTRIDE]      = pk2(ar3[0], ar3[1]);
      lds[nxt][base+96*LSTRIDE+1]    = pk2(ar3[2], ar3[3]);
      wc0 = wn0; wc1 = wn1; wc2 = wn2; wc3 = wn3;
    }
    __syncthreads();
  }

  // epilogue: C-frag lane l holds col = c*16 + (l&15), rows row0 + w*32 + rt*16 + (l>>4)*4 + i
  float numacc = 0.f, denacc = 0.f;
  {
    f32x4 a0s[2] = {acc00, acc10}, a1s[2] = {acc01, acc11};
    f32x4 a2s[2] = {acc02, acc12}, a3s[2] = {acc03, acc13};
    int wrow0 = row0 + w*32;
    for (int rt = 0; rt < 2; ++rt) {
      int rbase = wrow0 + rt*16 + lhi*4;
      for (int i = 0; i < 4; ++i) {
        int row = rbase + i;
        float sqv = sq[row];
        int hv = h[b*N_ + row];
        numacc += a0s[rt][i] * s_soft[row*32 + lr];
        numacc += a1s[rt][i] * s_soft[row*32 + 16 + lr];
        float v2 = a2s[rt][i], v3 = a3s[rt][i];
        denacc += (v2 + v3) * sqv;
        atomicAdd(&oal[hv*32 + lr], v2);
        atomicAdd(&oal[hv*32 + 16 + lr], v3);
      }
    }
  }
  for (int off = 32; off; off >>= 1) {
    numacc += __shfl_down(numacc, off);
    denacc += __shfl_down(denacc, off);
  }
  if (l == 0) { rn[w] = numacc; rd[w] = denacc; }
  __syncthreads();
  if (t == 0) {
    numden_p[bid] = rn[0]+rn[1]+rn[2]+rn[3];
    numden_p[1024 + bid] = rd[0]+rd[1]+rd[2]+rd[3];
  }
  for (int i = t; i < 1024; i += 256) oadjp[(size_t)bid*1024 + i] = oal[i];
}

// ---- K5: out_emb partials: [128 blocks][32*128] ----
__global__ void k_outemb(const float* __restrict__ emb, const int* __restrict__ h,
                         float* __restrict__ pemb) {
  __shared__ float accl[32*128];
  int t = threadIdx.x;
  for (int i = t; i < 4096; i += 256) accl[i] = 0.f;
  __syncthreads();
  int b = blockIdx.x >> 5;
  int n0 = (blockIdx.x & 31) * 128;
  int f = t & 127, rr = t >> 7;
  for (int it = 0; it < 64; ++it) {
    int n = n0 + it*2 + rr;
    float v = emb[((size_t)b*N_ + n)*F_ + f];
    int hv = h[b*N_ + n];
    atomicAdd(&accl[hv*128 + f], v);
  }
  __syncthreads();
  for (int i = t; i < 4096; i += 256) pemb[(size_t)blockIdx.x*4096 + i] = accl[i];
}

// ---- K6: reduce partials (blocks 0..15: oadj; 16..79: out_emb -> d_out) ----
__global__ void k_reduce(const float* __restrict__ oadjp, const float* __restrict__ pemb,
                         float* __restrict__ oadj, float* __restrict__ out_emb) {
  int blk = blockIdx.x;
  if (blk < 16) {
    int i = blk*256 + threadIdx.x;      // [0,4096)
    int b = i >> 10, ii = i & 1023;
    float s = 0.f;
    const float* p = oadjp + (size_t)(b*256)*1024 + ii;
    for (int j = 0; j < 256; ++j) s += p[(size_t)j*1024];
    oadj[i] = s;
  } else {
    int i = (blk-16)*256 + threadIdx.x; // [0,16384)
    int b = i >> 12, ii = i & 4095;
    float s = 0.f;
    const float* p = pemb + (size_t)(b*32)*4096 + ii;
    for (int j = 0; j < 32; ++j) s += p[(size_t)j*4096];
    out_emb[i] = s;
  }
}

// ---- K7: finalize out_adj + scalars ----
__global__ void k_final(const float* __restrict__ numden_p, const float* __restrict__ oadj,
                        const float* __restrict__ ss, float* __restrict__ dout) {
  __shared__ float dsh[128];
  __shared__ float red[256];
  __shared__ float nd[8];
  int t = threadIdx.x;
  if (t < 8) {
    int b = t & 3;
    const float* p = numden_p + (t >> 2)*1024 + b*256;
    float s = 0.f;
    for (int j = 0; j < 256; ++j) s += p[j];
    nd[t] = s;
  }
  if (t >= 64 && t < 192) {
    int i = t - 64;
    int b = i >> 5, k = i & 31;
    float s = 0.f;
    for (int l = 0; l < 32; ++l) if (l != k) s += oadj[b*1024 + k*32 + l];
    dsh[i] = sqrtf(s) + EPS_;
  }
  __syncthreads();
  for (int i = t; i < 4096; i += 256) {
    int b = i >> 10, k = (i >> 5) & 31, l = i & 31;
    float v = (k == l) ? 0.f : oadj[i] / (dsh[b*32+k] * dsh[b*32+l]);
    dout[16384 + i] = v;
  }
  float a = 0.f;
  for (int i = t; i < 1024; i += 256) { float v = ss[i]; a += v*v; }
  red[t] = a; __syncthreads();
  for (int s2 = 128; s2; s2 >>= 1) { if (t < s2) red[t] += red[t+s2]; __syncthreads(); }
  float fro = sqrtf(red[0]);
  __syncthreads();
  float c = 0.f;
  float inv = 1.f / fro;
  float dk = (float)(1.0 / sqrt(32.0));
  for (int i = t; i < 1024; i += 256) {
    int k = i >> 5, l = i & 31;
    float v = ss[i]*inv - ((k == l) ? dk : 0.f);
    c += v*v;
  }
  red[t] = c; __syncthreads();
  for (int s2 = 128; s2; s2 >>= 1) { if (t < s2) red[t] += red[t+s2]; __syncthreads(); }
  if (t == 0) {
    dout[544769] = sqrtf(red[0]);
    float s = 0.f;
    for (int b = 0; b < 4; ++b) s += nd[b] / nd[4+b];
    dout[544768] = -s*0.25f;
  }
}

extern "C" void kernel_launch(void* const* d_in, const int* in_sizes, int n_in,
                              void* d_out, int out_size, void* d_ws, size_t ws_size,
                              hipStream_t stream) {
  const float* emb    = (const float*)d_in[0];
  const float* adj    = (const float*)d_in[1];
  const float* logits = (const float*)d_in[2];
  const float* gum    = (const float*)d_in[3];
  float* out = (float*)d_out;
  float* ws  = (float*)d_ws;

  float t1 = 0.99995f;
  float t2 = (float)(0.99995 * 0.99995);

  float* s_soft = ws + WS_SSOFT;
  float* sq     = ws + WS_SQ;
  float* ss     = ws + WS_SS;
  bf16x8* wf    = (bf16x8*)(ws + WS_WF);
  float* oadjp  = ws + WS_OADJP;
  float* ndp    = ws + WS_NUMDEN;
  float* pemb   = ws + WS_PEMB;
  float* oadj   = ws + WS_OADJ;
  int* hbuf     = (int*)(ws + WS_H);

  (void)hipMemsetAsync(ss, 0, 1024 * sizeof(float), stream);

  k_ssoft <<<64, 256, 0, stream>>>(logits, s_soft, sq, ss, t2);
  k_gumbel<<<64, 256, 0, stream>>>(logits, gum, out + 20480, hbuf, t1);
  k_wfrag <<<512, 256, 0, stream>>>(s_soft, hbuf, wf);
  k_gemm  <<<1024, 256, 0, stream>>>(adj, wf, s_soft, sq, hbuf, ndp, oadjp);
  k_outemb<<<128, 256, 0, stream>>>(emb, hbuf, pemb);
  k_reduce<<<80, 256, 0, stream>>>(oadjp, pemb, oadj, out);
  k_final <<<1, 256, 0, stream>>>(ndp, oadj, ss, out);
}